// Round 13
// baseline (1452.068 us; speedup 1.0000x reference)
//
#include <hip/hip_runtime.h>
#include <cstdint>

typedef _Float16 half8 __attribute__((ext_vector_type(8)));
typedef _Float16 h2f __attribute__((ext_vector_type(2)));
typedef float f32x4 __attribute__((ext_vector_type(4)));

__device__ __forceinline__ float leakyf(float v){ return v > 0.f ? v : 0.01f*v; }
__device__ __forceinline__ float actf(float v, int act){
  if (act == 1) return fmaxf(v, 0.f);
  if (act == 2) return leakyf(v);
  return v;
}
__device__ __forceinline__ unsigned pkh(float a, float b){
  h2f p; p[0]=(_Float16)a; p[1]=(_Float16)b; return __builtin_bit_cast(unsigned, p);
}
__device__ __forceinline__ h2f uph(unsigned u){ return __builtin_bit_cast(h2f, u); }

__device__ __forceinline__ void gl_lds16(const void* g, void* l){
  __builtin_amdgcn_global_load_lds((const __attribute__((address_space(1))) void*)g,
                                   (__attribute__((address_space(3))) void*)l, 16, 0, 0);
}

// stage one 128x64(half) tile (16KB) into LDS, row-major with XOR chunk swizzle.
// physical byte = row*128 + pchunk*16; content = global chunk (pchunk ^ (row&7)).
__device__ __forceinline__ void stage64(const _Float16* __restrict__ g, long ld,
                                        int r0, long k0, _Float16* lbuf, int tid){
  #pragma unroll
  for (int i=0;i<4;++i){
    int gidx = i*256 + tid;
    int row = gidx >> 3, pc = gidx & 7;
    int lc = pc ^ (row & 7);
    gl_lds16(g + (size_t)(r0+row)*ld + k0 + lc*8, (char*)lbuf + i*4096 + (size_t)tid*16);
  }
}
// 64-row variant (8KB)
__device__ __forceinline__ void stage64h(const _Float16* __restrict__ g, long ld,
                                         int r0, long k0, _Float16* lbuf, int tid){
  #pragma unroll
  for (int i=0;i<2;++i){
    int gidx = i*256 + tid;
    int row = gidx >> 3, pc = gidx & 7;
    int lc = pc ^ (row & 7);
    gl_lds16(g + (size_t)(r0+row)*ld + k0 + lc*8, (char*)lbuf + i*4096 + (size_t)tid*16);
  }
}

// bijective XCD-chunked swizzle (m204)
__device__ __forceinline__ void xcd_swz(int& bx, int& by){
  int nx = gridDim.x;
  int nwg = nx * gridDim.y;
  int lid = blockIdx.y*nx + blockIdx.x;
  int q = nwg >> 3, r = nwg & 7;
  int xcd = lid & 7, idx = lid >> 3;
  int w = (xcd < r ? xcd*(q+1) : r*(q+1) + (xcd-r)*q) + idx;
  bx = w % nx; by = w / nx;
}

// ---------------- graph build ----------------
__global__ void k_ginit(int* deg_out, int* deg_in, int* cursor, float* colsum, int n){
  int i = blockIdx.x*blockDim.x + threadIdx.x;
  if (i < n){ deg_out[i] = 1; deg_in[i] = 1; cursor[i] = 0; }
  if (i < 16) colsum[i] = 0.f;
}
__global__ void k_count(const int* __restrict__ src, const int* __restrict__ dst,
                        int* deg_out, int* deg_in, int e){
  int i = blockIdx.x*blockDim.x + threadIdx.x;
  if (i < e){ atomicAdd(&deg_out[src[i]], 1); atomicAdd(&deg_in[dst[i]], 1); }
}
__global__ void k_scan(const int* __restrict__ deg, int* rp, int n){
  __shared__ int sums[1024];
  int t = threadIdx.x;
  int per = (n + 1023)/1024;
  int base = t*per;
  int s = 0;
  for (int i = 0; i < per; ++i){ int j = base+i; if (j < n) s += deg[j]; }
  sums[t] = s; __syncthreads();
  for (int off = 1; off < 1024; off <<= 1){
    int v = 0;
    if (t >= off) v = sums[t-off];
    __syncthreads();
    if (t >= off) sums[t] += v;
    __syncthreads();
  }
  int run = (t == 0) ? 0 : sums[t-1];
  for (int i = 0; i < per; ++i){ int j = base+i; if (j < n){ rp[j] = run; run += deg[j]; } }
  if (t == 1023) rp[n] = sums[1023];
}
__global__ void k_fill(const int* __restrict__ src, const int* __restrict__ dst,
                       const int* __restrict__ rp, int* cursor, int* ci, int e, int n){
  int i = blockIdx.x*blockDim.x + threadIdx.x;
  if (i >= e + n) return;
  int s, d;
  if (i < e){ s = src[i]; d = dst[i]; } else { s = d = i - e; }
  int pos = atomicAdd(&cursor[d], 1);
  ci[rp[d] + pos] = s;
}
__global__ void k_norms(const int* deg_out, const int* deg_in, float* nsrc, float* ndst, int n){
  int i = blockIdx.x*blockDim.x + threadIdx.x;
  if (i < n){ nsrc[i] = rsqrtf((float)deg_out[i]); ndst[i] = rsqrtf((float)deg_in[i]); }
}

// ---------------- conversions ----------------
__global__ void k_conv_a(const float* __restrict__ in, _Float16* __restrict__ out,
                         int M, int K, int Mp, int Kp){
  long idx = (long)blockIdx.x*blockDim.x + threadIdx.x;
  long total = (long)Mp*(Kp/8);
  if (idx >= total) return;
  int kp8 = Kp/8;
  int m = (int)(idx / kp8);
  int k8 = (int)(idx % kp8) * 8;
  half8 o;
  #pragma unroll
  for (int j=0;j<8;++j){
    int k = k8+j;
    o[j] = (_Float16)((m<M && k<K) ? in[(size_t)m*K + k] : 0.f);
  }
  *(half8*)&out[(size_t)m*Kp + k8] = o;
}

// batched transpose-convert: 9 weight matrices in one launch
struct ConvDesc { const float* in; _Float16* out; int K, N, Np, Kp; };
struct ConvPack { ConvDesc d[9]; int tile0[10]; };
__global__ __launch_bounds__(256) void k_conv_bt_all(ConvPack p){
  __shared__ float t[32][33];
  int tile = blockIdx.x;
  int di = 0;
  while (di < 8 && tile >= p.tile0[di+1]) ++di;
  ConvDesc d = p.d[di];
  int lt = tile - p.tile0[di];
  int ntx = d.Kp/32;
  int kb = (lt % ntx)*32, nb = (lt / ntx)*32;
  int tx = threadIdx.x & 31, ty = threadIdx.x >> 5;
  for (int r=ty; r<32; r+=8){
    int k = kb+r, n = nb+tx;
    t[r][tx] = (k<d.K && n<d.N) ? d.in[(size_t)k*d.N+n] : 0.f;
  }
  __syncthreads();
  for (int r=ty; r<32; r+=8){
    int n = nb+r, k = kb+tx;
    if (n<d.Np && k<d.Kp) d.out[(size_t)n*d.Kp+k] = (_Float16)t[tx][r];
  }
}

// build Wc [128 x 3136] fp16: packed mlw + block-diag g5 over padded segment layout
__global__ void k_build_wc(const float* __restrict__ mlw, const float* __restrict__ g5,
                           _Float16* __restrict__ wc){
  int idx = blockIdx.x*blockDim.x + threadIdx.x;
  if (idx >= 128*3136) return;
  int c = idx / 3136, k = idx - (idx/3136)*3136;
  int seg = -1, real_k = 0;
  if (k < 512){ if (k < 500){ seg=0; real_k=k; } }
  else if (k < 1024){ int kk=k-512; if (kk<500){ seg=1; real_k=500+kk; } }
  else if (k < 3072){ int kk=k-1024; if (kk<2000){ seg=2; real_k=1000+kk; } }
  else { int kk=k-3072; if (kk<10){ seg=3; real_k=3000+kk; } else if (kk<20){ seg=4; real_k=3010+kk-10; } }
  float val = 0.f;
  if (seg >= 0){
    if (c < 5) val = mlw[(size_t)real_k*5 + c];
    else if (c < 55){ int t=c-5; if (t/10 == seg) val = g5[(size_t)real_k*10 + (t-(t/10)*10)]; }
  }
  wc[(size_t)c*3136 + k] = (_Float16)val;
}

// fragment read + MFMA for BK=64 swizzled tile (128-row A/B)
#define MFMA_K64(BUF_A, BUF_B) \
  _Pragma("unroll") \
  for (int kk=0; kk<2; ++kk){ \
    half8 af[4], bf[4]; \
    _Pragma("unroll") \
    for (int mi=0;mi<4;++mi){ \
      int R = wr*64 + mi*16 + (l&15); \
      int p = (kk*4 + (l>>4)) ^ (R&7); \
      af[mi] = *(const half8*)&(BUF_A)[R*64 + p*8]; \
    } \
    _Pragma("unroll") \
    for (int nj=0;nj<4;++nj){ \
      int R = wc*64 + nj*16 + (l&15); \
      int p = (kk*4 + (l>>4)) ^ (R&7); \
      bf[nj] = *(const half8*)&(BUF_B)[R*64 + p*8]; \
    } \
    _Pragma("unroll") \
    for (int mi=0;mi<4;++mi) \
      _Pragma("unroll") \
      for (int nj=0;nj<4;++nj) \
        acc[mi][nj] = __builtin_amdgcn_mfma_f32_16x16x32_f16(af[mi], bf[nj], acc[mi][nj], 0,0,0); \
  }

// ---------------- fp16 MFMA GEMM: Ch = act(A @ B^T + bias), fp16 out ----------------
template<int ACT, bool BIAS>
__global__ __launch_bounds__(256) void k_hgemm(
    const _Float16* __restrict__ A, const _Float16* __restrict__ BT,
    const float* __restrict__ bias, _Float16* __restrict__ Ch,
    int M, int Nvalid, long Np, long Kp, long lda)
{
  __shared__ __align__(16) _Float16 Asm[8192];
  __shared__ __align__(16) _Float16 Bsm[8192];
  int bx, by; xcd_swz(bx, by);
  const int m0 = by*128, n0 = bx*128;
  const int tid = threadIdx.x;
  const int l = tid & 63, w = tid >> 6;
  const int wr = w >> 1, wc = w & 1;
  f32x4 acc[4][4] = {};

  for (long k0 = 0; k0 < Kp; k0 += 64){
    stage64(A,  lda, m0, k0, Asm, tid);
    stage64(BT, Kp,  n0, k0, Bsm, tid);
    __syncthreads();
    MFMA_K64(Asm, Bsm)
    __syncthreads();
  }

  const int cr = (l>>4)*4, cc = l&15;
  #pragma unroll
  for (int mi=0;mi<4;++mi){
    #pragma unroll
    for (int nj=0;nj<4;++nj){
      int cbase = n0 + wc*64 + nj*16 + cc;
      bool cvalid = cbase < Nvalid;
      #pragma unroll
      for (int q=0;q<4;++q){
        int r = m0 + wr*64 + mi*16 + cr + q;
        float v = acc[mi][nj][q];
        if (BIAS && cvalid) v += bias[cbase];
        if (ACT==1) v = fmaxf(v,0.f); else if (ACT==2) v = leakyf(v);
        if (!cvalid) v = 0.f;
        Ch[(size_t)r*Np + cbase] = (_Float16)(r < M ? v : 0.f);
      }
    }
  }
}

// ---------------- dual GEMM: cols 0-511 = relu(x@ew1+eb1), cols 512-1023 = x@g1 ----------------
__global__ __launch_bounds__(256) void k_hgemm_dual(
    const _Float16* __restrict__ A, const _Float16* __restrict__ BT,
    const float* __restrict__ eb1, _Float16* __restrict__ Ch, int M)
{
  const long Kp = 2048;
  __shared__ __align__(16) _Float16 Asm[8192];
  __shared__ __align__(16) _Float16 Bsm[8192];
  int bx, by; xcd_swz(bx, by);
  const int m0 = by*128, n0 = bx*128;
  const int tid = threadIdx.x;
  const int l = tid & 63, w = tid >> 6;
  const int wr = w >> 1, wc = w & 1;
  f32x4 acc[4][4] = {};

  for (long k0 = 0; k0 < Kp; k0 += 64){
    stage64(A,  Kp, m0, k0, Asm, tid);
    stage64(BT, Kp, n0, k0, Bsm, tid);
    __syncthreads();
    MFMA_K64(Asm, Bsm)
    __syncthreads();
  }

  const int cr = (l>>4)*4, cc = l&15;
  #pragma unroll
  for (int mi=0;mi<4;++mi){
    #pragma unroll
    for (int nj=0;nj<4;++nj){
      int cbase = n0 + wc*64 + nj*16 + cc;
      bool hi = cbase >= 512;
      int cl = hi ? cbase - 512 : cbase;
      bool cvalid = cl < 500;
      #pragma unroll
      for (int q=0;q<4;++q){
        int r = m0 + wr*64 + mi*16 + cr + q;
        float v = acc[mi][nj][q];
        if (!hi && cvalid){ v += eb1[cl]; v = fmaxf(v, 0.f); }
        if (!cvalid) v = 0.f;
        Ch[(size_t)r*1024 + cbase] = (_Float16)(r < M ? v : 0.f);
      }
    }
  }
}

// ---------------- f32-out GEMM with LDS-transposed coalesced epilogue (x_bar) ----------------
__global__ __launch_bounds__(256) void k_hgemm_f32t(
    const _Float16* __restrict__ A, const _Float16* __restrict__ BT,
    const float* __restrict__ bias, float* __restrict__ C,
    int M, int Nvalid, long Kp, long lda)
{
  __shared__ __align__(16) _Float16 Asm[8192];
  __shared__ __align__(16) _Float16 Bsm[8192];
  __shared__ __align__(16) float scr[16*128];
  int bx, by; xcd_swz(bx, by);
  const int m0 = by*128, n0 = bx*128;
  const int tid = threadIdx.x;
  const int l = tid & 63, w = tid >> 6;
  const int wr = w >> 1, wc = w & 1;
  f32x4 acc[4][4] = {};

  for (long k0 = 0; k0 < Kp; k0 += 64){
    stage64(A,  lda, m0, k0, Asm, tid);
    stage64(BT, Kp,  n0, k0, Bsm, tid);
    __syncthreads();
    MFMA_K64(Asm, Bsm)
    __syncthreads();
  }

  const int cr = (l>>4)*4, cc = l&15;
  for (int p = 0; p < 8; ++p){
    if (wr == (p>>2)){
      int mi = p & 3;
      #pragma unroll
      for (int nj=0;nj<4;++nj){
        int cb = wc*64 + nj*16 + cc;
        float bv = (n0+cb < Nvalid) ? bias[n0+cb] : 0.f;
        #pragma unroll
        for (int q=0;q<4;++q)
          scr[(cr+q)*128 + cb] = acc[mi][nj][q] + bv;
      }
    }
    __syncthreads();
    #pragma unroll
    for (int j=0;j<2;++j){
      int flat = (tid + j*256)*4;
      int rl = flat >> 7, col = flat & 127;
      int r = m0 + p*16 + rl;
      int cb = n0 + col;
      if (r < M && cb < Nvalid)
        *(f32x4*)&C[(size_t)r*Nvalid + cb] = *(const f32x4*)&scr[flat];
    }
    __syncthreads();
  }
}

// ---------------- up5 GEMM, 128x64 tile (4 waves on M), split-K x2 ----------------
__global__ __launch_bounds__(256) void k_hgemm_up5(
    const _Float16* __restrict__ z1h, const _Float16* __restrict__ z2h,
    const _Float16* __restrict__ z3h, const _Float16* __restrict__ z4zh,
    const _Float16* __restrict__ Wc, float* __restrict__ Y, int M, int Mp)
{
  __shared__ __align__(16) _Float16 Asm[8192];   // 128 x 64
  __shared__ __align__(16) _Float16 Bsm[4096];   // 64 x 64
  int bx, by; xcd_swz(bx, by);   // bx in {0,1}: K-half
  const int m0 = by*128;
  const int tid = threadIdx.x;
  const int l = tid & 63, w = tid >> 6;
  const int wr = w;              // 4 waves stacked on M; wave tile 32x64
  f32x4 acc[2][4] = {};

  auto stage_a = [&](int k0, _Float16* lbuf){
    const _Float16* ab; long astr; int kk;
    if (k0 < 512){ ab=z1h; astr=512; kk=k0; }
    else if (k0 < 1024){ ab=z2h; astr=512; kk=k0-512; }
    else if (k0 < 3072){ ab=z3h; astr=2048; kk=k0-1024; }
    else { ab=z4zh; astr=64; kk=k0-3072; }
    stage64(ab, astr, m0, kk, lbuf, tid);
  };

  const int kbase = bx*1536;
  const int ntl = bx ? 25 : 24;
  for (int t = 0; t < ntl; ++t){
    int k0 = kbase + t*64;
    stage_a(k0, Asm);
    stage64h(Wc, 3136, 0, k0, Bsm, tid);
    __syncthreads();
    #pragma unroll
    for (int kk=0; kk<2; ++kk){
      half8 af[2], bf[4];
      #pragma unroll
      for (int mi=0;mi<2;++mi){
        int R = wr*32 + mi*16 + (l&15);
        int p = (kk*4 + (l>>4)) ^ (R&7);
        af[mi] = *(const half8*)&Asm[R*64 + p*8];
      }
      #pragma unroll
      for (int nj=0;nj<4;++nj){
        int R = nj*16 + (l&15);
        int p = (kk*4 + (l>>4)) ^ (R&7);
        bf[nj] = *(const half8*)&Bsm[R*64 + p*8];
      }
      #pragma unroll
      for (int mi=0;mi<2;++mi)
        #pragma unroll
        for (int nj=0;nj<4;++nj)
          acc[mi][nj] = __builtin_amdgcn_mfma_f32_16x16x32_f16(af[mi], bf[nj], acc[mi][nj], 0,0,0);
    }
    __syncthreads();
  }

  float* Yh = Y + (size_t)bx*Mp*64;
  const int cr = (l>>4)*4, cc = l&15;
  #pragma unroll
  for (int mi=0;mi<2;++mi){
    #pragma unroll
    for (int nj=0;nj<4;++nj){
      int cbase = nj*16 + cc;
      #pragma unroll
      for (int q=0;q<4;++q){
        int r = m0 + wr*32 + mi*16 + cr + q;
        if (r < M) Yh[(size_t)r*64 + cbase] = acc[mi][nj][q];
      }
    }
  }
}

// epilogue: sum split-K halves; u = l2(softmax(leaky(logits+mlb))); pre5 = sum_i u_i*P_i
__global__ void k_up5_fin(const float* __restrict__ Y, const float* __restrict__ mlb,
                          float* __restrict__ pre5, int M, int Mp){
  int row = blockIdx.x*blockDim.x + threadIdx.x;
  if (row >= M) return;
  const float* y0 = Y + (size_t)row*64;
  const float* y1 = Y + (size_t)Mp*64 + (size_t)row*64;
  float y[64];
  #pragma unroll
  for (int c=0;c<55;++c) y[c] = y0[c] + y1[c];
  float v[5]; float mx = -1e30f;
  #pragma unroll
  for (int c=0;c<5;++c){ float t = leakyf(y[c] + mlb[c]); v[c]=t; mx=fmaxf(mx,t); }
  float ss=0.f;
  #pragma unroll
  for (int c=0;c<5;++c){ v[c]=expf(v[c]-mx); ss += v[c]*v[c]; }
  float inv = rsqrtf(fmaxf(ss,1e-30f));
  #pragma unroll
  for (int c=0;c<5;++c) v[c] *= inv;
  #pragma unroll
  for (int c=0;c<10;++c){
    float s = 0.f;
    #pragma unroll
    for (int i=0;i<5;++i) s += v[i]*y[5 + 10*i + c];
    pre5[(size_t)row*10 + c] = s;
  }
}

// zlat tail: z4zh[row][10:20]=zlat, [20:64)=0  (cols 0-9 written by k_spmm10z4)
__global__ void k_tailz(const float* __restrict__ zlat, _Float16* __restrict__ z4zh, int M){
  int idx = blockIdx.x*blockDim.x + threadIdx.x;
  if (idx >= M*54) return;
  int row = idx/54, j = idx - row*54;
  float v = (j < 10) ? zlat[(size_t)row*10 + j] : 0.f;
  z4zh[(size_t)row*64 + 10 + j] = (_Float16)v;
}

// ---------------- skinny 10-out GEMM, fp16 A (half8 loads), LDS K padded to 2048 ----------------
__global__ __launch_bounds__(256) void k_skinny10_h(
    const _Float16* __restrict__ A, long lda, const float* __restrict__ W, int K,
    const float* __restrict__ bias, float* __restrict__ out, int M, int act)
{
  __shared__ float wl[10*2048];
  int tid = threadIdx.x;
  for (int idx = tid; idx < 2048*10; idx += 256){
    int k = idx & 2047, c = idx >> 11;
    wl[c*2048 + k] = (k < K) ? W[(size_t)k*10 + c] : 0.f;
  }
  __syncthreads();
  int wv = tid >> 6, lane = tid & 63;
  int stride = gridDim.x*4;
  for (int row = blockIdx.x*4 + wv; row < M; row += stride){
    const _Float16* a = A + (size_t)row*lda;
    float acc[10];
    #pragma unroll
    for (int c=0;c<10;++c) acc[c]=0.f;
    #pragma unroll
    for (int it=0; it<4; ++it){
      int k0 = lane*8 + it*512;
      half8 a8 = *(const half8*)(a + k0);
      #pragma unroll
      for (int j=0;j<8;++j){
        float av = (float)a8[j];
        #pragma unroll
        for (int c=0;c<10;++c) acc[c] += av*wl[c*2048 + k0 + j];
      }
    }
    #pragma unroll
    for (int c=0;c<10;++c){
      #pragma unroll
      for (int off=32; off; off>>=1) acc[c] += __shfl_down(acc[c], off);
    }
    if (lane == 0){
      #pragma unroll
      for (int c=0;c<10;++c){
        float v = acc[c] + (bias ? bias[c] : 0.f);
        out[(size_t)row*10 + c] = actf(v, act);
      }
    }
  }
}

// ---------------- fused gate3 + mix3@g4 (half8 loads, K padded 2048) ----------------
__global__ __launch_bounds__(256) void k_fused3(
    const _Float16* __restrict__ tra, const _Float16* __restrict__ zin,
    const float* __restrict__ m3w, const float* __restrict__ b3,
    const float* __restrict__ g4, float* __restrict__ pre4, int M)
{
  const int K = 2000;
  __shared__ unsigned g4l[5*2048];
  __shared__ unsigned mt01[2048];
  __shared__ unsigned mz01[2048];
  int tid = threadIdx.x;
  for (int k = tid; k < 2048; k += 256){
    bool v = k < K;
    mt01[k] = v ? pkh(m3w[2*k],     m3w[2*k+1])     : 0u;
    mz01[k] = v ? pkh(m3w[2*(K+k)], m3w[2*(K+k)+1]) : 0u;
  }
  for (int idx = tid; idx < 2048*5; idx += 256){
    int k = idx & 2047, jp = idx >> 11;
    g4l[jp*2048 + k] = (k < K) ? pkh(g4[(size_t)k*10 + 2*jp], g4[(size_t)k*10 + 2*jp + 1]) : 0u;
  }
  __syncthreads();
  int wv = tid >> 6, lane = tid & 63;
  int stride = gridDim.x*4;
  for (int row = blockIdx.x*4 + wv; row < M; row += stride){
    const _Float16* tr = tra + (size_t)row*2048;
    const _Float16* zr = zin + (size_t)row*2048;
    float a0=0.f, a1=0.f;
    float t4[10], z4a[10];
    #pragma unroll
    for (int c=0;c<10;++c){ t4[c]=0.f; z4a[c]=0.f; }
    #pragma unroll
    for (int it=0; it<4; ++it){
      int k0 = lane*8 + it*512;
      half8 t8 = *(const half8*)(tr + k0);
      half8 z8 = *(const half8*)(zr + k0);
      #pragma unroll
      for (int j=0;j<8;++j){
        int k = k0 + j;
        float t = (float)t8[j], z = (float)z8[j];
        h2f mt = uph(mt01[k]); h2f mz = uph(mz01[k]);
        a0 += t*(float)mt[0] + z*(float)mz[0];
        a1 += t*(float)mt[1] + z*(float)mz[1];
        #pragma unroll
        for (int jp=0;jp<5;++jp){
          h2f p = uph(g4l[jp*2048 + k]);
          float p0 = (float)p[0], p1 = (float)p[1];
          t4[2*jp]   += t*p0;  t4[2*jp+1]  += t*p1;
          z4a[2*jp]  += z*p0;  z4a[2*jp+1] += z*p1;
        }
      }
    }
    #pragma unroll
    for (int off=32; off; off>>=1){
      a0 += __shfl_down(a0,off); a1 += __shfl_down(a1,off);
      #pragma unroll
      for (int c=0;c<10;++c){
        t4[c]  += __shfl_down(t4[c], off);
        z4a[c] += __shfl_down(z4a[c], off);
      }
    }
    if (lane == 0){
      float s0 = leakyf(a0 + b3[0]);
      float s1 = leakyf(a1 + b3[1]);
      float mx = fmaxf(s0, s1);
      float e0 = expf(s0-mx), e1 = expf(s1-mx);
      float inv = rsqrtf(fmaxf(e0*e0 + e1*e1, 1e-30f));
      float mzc = e0*inv, mtc = e1*inv;
      #pragma unroll
      for (int c=0;c<10;++c)
        pre4[(size_t)row*10 + c] = mzc*z4a[c] + mtc*t4[c];
    }
  }
}

// ---------------- fused gate+mix, wave per row (W=500, half8), fp16 in/out ----------------
__global__ __launch_bounds__(256) void k_gate_mix_w(
    const _Float16* __restrict__ tra, long Wpa, const _Float16* __restrict__ zin, long Wpz,
    const float* __restrict__ w, const float* __restrict__ b,
    _Float16* __restrict__ mix, int W, long Wpo, int M)
{
  int wv = threadIdx.x >> 6, lane = threadIdx.x & 63;
  int row = blockIdx.x*4 + wv;
  if (row >= M) return;
  const _Float16* tr = tra + (size_t)row*Wpa;
  const _Float16* zr = zin + (size_t)row*Wpz;
  half8 t8 = *(const half8*)(tr + lane*8);
  half8 z8 = *(const half8*)(zr + lane*8);
  float a0=0.f, a1=0.f;
  #pragma unroll
  for (int j=0;j<8;++j){
    int k = lane*8 + j;
    if (k < W){
      float t = (float)t8[j], zv = (float)z8[j];
      a0 += t*w[2*k]   + zv*w[2*(W+k)];
      a1 += t*w[2*k+1] + zv*w[2*(W+k)+1];
    }
  }
  #pragma unroll
  for (int m=1;m<64;m<<=1){ a0 += __shfl_xor(a0,m); a1 += __shfl_xor(a1,m); }
  float s0 = leakyf(a0 + b[0]);
  float s1 = leakyf(a1 + b[1]);
  float mx = fmaxf(s0,s1);
  float e0 = expf(s0-mx), e1 = expf(s1-mx);
  float inv = rsqrtf(fmaxf(e0*e0+e1*e1, 1e-30f));
  float mz = e0*inv, mt = e1*inv;
  half8 o;
  #pragma unroll
  for (int j=0;j<8;++j)
    o[j] = (_Float16)(mz*(float)z8[j] + mt*(float)t8[j]);   // pads are zero in both inputs
  *(half8*)(mix + (size_t)row*Wpo + lane*8) = o;
}

// ---------------- SpMM gather, fp16x2 loads, 4-edge unrolled; fp16 out ----------------
template<int ACT>
__global__ void k_spmm2(const _Float16* __restrict__ h, long Wpi, const int* __restrict__ rp,
                        const int* __restrict__ ci, const float* __restrict__ nsrc,
                        const float* __restrict__ ndst, _Float16* __restrict__ outh,
                        int W, long Wpo)
{
  int row = blockIdx.x;
  int tid = threadIdx.x;
  int c = tid*2;
  int e0 = rp[row], e1 = rp[row+1];
  float a0=0.f, a1=0.f;
  int e = e0;
  for (; e+4 <= e1; e+=4){
    int s0=ci[e], s1=ci[e+1], s2=ci[e+2], s3=ci[e+3];
    float w0=nsrc[s0], w1=nsrc[s1], w2=nsrc[s2], w3=nsrc[s3];
    h2f p0 = *(const h2f*)(h + (size_t)s0*Wpi + c);
    h2f p1 = *(const h2f*)(h + (size_t)s1*Wpi + c);
    h2f p2 = *(const h2f*)(h + (size_t)s2*Wpi + c);
    h2f p3 = *(const h2f*)(h + (size_t)s3*Wpi + c);
    a0 += w0*(float)p0[0] + w1*(float)p1[0] + w2*(float)p2[0] + w3*(float)p3[0];
    a1 += w0*(float)p0[1] + w1*(float)p1[1] + w2*(float)p2[1] + w3*(float)p3[1];
  }
  for (; e < e1; ++e){
    int s = ci[e];
    float ns = nsrc[s];
    h2f p = *(const h2f*)(h + (size_t)s*Wpi + c);
    a0 += ns*(float)p[0];
    a1 += ns*(float)p[1];
  }
  float nd = ndst[row];
  a0 = actf(a0*nd, ACT); a1 = actf(a1*nd, ACT);
  h2f o;
  o[0] = (_Float16)(c   < W ? a0 : 0.f);
  o[1] = (_Float16)(c+1 < W ? a1 : 0.f);
  *(h2f*)(outh + (size_t)row*Wpo + c) = o;
}

// ---------------- SpMM width 10, f32 out ----------------
template<int ACT>
__global__ void k_spmm10(const float* __restrict__ h, const int* __restrict__ rp,
                         const int* __restrict__ ci, const float* __restrict__ nsrc,
                         const float* __restrict__ ndst, float* __restrict__ out, int n)
{
  int idx = blockIdx.x*blockDim.x + threadIdx.x;
  if (idx >= n*10) return;
  int row = idx/10, c = idx - row*10;
  int e0 = rp[row], e1 = rp[row+1];
  float acc = 0.f;
  int e = e0;
  for (; e+4 <= e1; e+=4){
    int s0=ci[e], s1=ci[e+1], s2=ci[e+2], s3=ci[e+3];
    acc += nsrc[s0]*h[(size_t)s0*10 + c] + nsrc[s1]*h[(size_t)s1*10 + c]
         + nsrc[s2]*h[(size_t)s2*10 + c] + nsrc[s3]*h[(size_t)s3*10 + c];
  }
  for (; e < e1; ++e){
    int s = ci[e];
    acc += nsrc[s]*h[(size_t)s*10 + c];
  }
  out[idx] = actf(acc*ndst[row], ACT);
}

// ---------------- SpMM width 10, writes z4 directly as fp16 into z4zh cols 0-9 ----------------
__global__ void k_spmm10z4(const float* __restrict__ h, const int* __restrict__ rp,
                           const int* __restrict__ ci, const float* __restrict__ nsrc,
                           const float* __restrict__ ndst, _Float16* __restrict__ z4zh, int n)
{
  int idx = blockIdx.x*blockDim.x + threadIdx.x;
  if (idx >= n*10) return;
  int row = idx/10, c = idx - row*10;
  int e0 = rp[row], e1 = rp[row+1];
  float acc = 0.f;
  int e = e0;
  for (; e+4 <= e1; e+=4){
    int s0=ci[e], s1=ci[e+1], s2=ci[e+2], s3=ci[e+3];
    acc += nsrc[s0]*h[(size_t)s0*10 + c] + nsrc[s1]*h[(size_t)s1*10 + c]
         + nsrc[s2]*h[(size_t)s2*10 + c] + nsrc[s3]*h[(size_t)s3*10 + c];
  }
  for (; e < e1; ++e){
    int s = ci[e];
    acc += nsrc[s]*h[(size_t)s*10 + c];
  }
  z4zh[(size_t)row*64 + c] = (_Float16)leakyf(acc*ndst[row]);
}

// ---------------- decoder layer 1: weights in registers ----------------
__global__ __launch_bounds__(512) void k_broad_reg(
    const float* __restrict__ Z, const float* __restrict__ W, const float* __restrict__ bias,
    _Float16* __restrict__ out, int M, int Mp, int Cc, int Cp)
{
  int tid = threadIdx.x;
  float wr[4][10], bv[4];
  #pragma unroll
  for (int j=0;j<4;++j){
    int c = tid + j*512;
    bool v = c < Cc;
    bv[j] = v ? bias[c] : 0.f;
    #pragma unroll
    for (int q=0;q<10;++q) wr[j][q] = v ? W[(size_t)q*Cc + c] : 0.f;
  }
  for (int row = blockIdx.x; row < Mp; row += gridDim.x){
    float zr[10];
    bool rv = row < M;
    #pragma unroll
    for (int q=0;q<10;++q) zr[q] = rv ? Z[(size_t)row*10 + q] : 0.f;
    #pragma unroll
    for (int j=0;j<4;++j){
      int c = tid + j*512;
      float v = bv[j];
      #pragma unroll
      for (int q=0;q<10;++q) v += zr[q]*wr[j][q];
      v = fmaxf(v, 0.f);
      out[(size_t)row*Cp + c] = (_Float16)((rv && c < Cc) ? v : 0.f);
    }
  }
}

__global__ void k_softmax10(const float* __restrict__ h, float* __restrict__ out, int M){
  int row = blockIdx.x*blockDim.x + threadIdx.x;
  if (row >= M) return;
  float v[10]; float mx=-1e30f;
  #pragma unroll
  for (int j=0;j<10;++j){ v[j]=h[(size_t)row*10+j]; mx=fmaxf(mx,v[j]); }
  float s=0.f;
  #pragma unroll
  for (int j=0;j<10;++j){ v[j]=expf(v[j]-mx); s+=v[j]; }
  float inv=1.f/s;
  #pragma unroll
  for (int j=0;j<10;++j) out[(size_t)row*10+j]=v[j]*inv;
}

__global__ void k_q(const float* __restrict__ z, const float* __restrict__ cluster,
                    float* __restrict__ qout, float* __restrict__ colsum, int M)
{
  __shared__ float part[10];
  if (threadIdx.x < 10) part[threadIdx.x] = 0.f;
  __syncthreads();
  int row = blockIdx.x*blockDim.x + threadIdx.x;
  if (row < M){
    float zr[10];
    #pragma unroll
    for (int j=0;j<10;++j) zr[j] = z[(size_t)row*10+j];
    float qv[10]; float s=0.f;
    #pragma unroll
    for (int k=0;k<10;++k){
      float d2=0.f;
      #pragma unroll
      for (int j=0;j<10;++j){ float t = zr[j]-cluster[k*10+j]; d2 += t*t; }
      float qq = 1.f/(1.f+d2);
      qv[k]=qq; s+=qq;
    }
    float inv = 1.f/s;
    #pragma unroll
    for (int k=0;k<10;++k){
      float val = qv[k]*inv;
      qout[(size_t)row*10+k] = val;
      atomicAdd(&part[k], val);
    }
  }
  __syncthreads();
  if (threadIdx.x < 10) atomicAdd(&colsum[threadIdx.x], part[threadIdx.x]);
}

__global__ void k_p(const float* __restrict__ q, const float* __restrict__ colsum,
                    float* __restrict__ pout, int M){
  int row = blockIdx.x*blockDim.x + threadIdx.x;
  if (row >= M) return;
  float w[10]; float s=0.f;
  #pragma unroll
  for (int k=0;k<10;++k){ float qq=q[(size_t)row*10+k]; float ww=qq*qq/colsum[k]; w[k]=ww; s+=ww; }
  float inv=1.f/s;
  #pragma unroll
  for (int k=0;k<10;++k) pout[(size_t)row*10+k]=w[k]*inv;
}

extern "C" void kernel_launch(void* const* d_in, const int* in_sizes, int n_in,
                              void* d_out, int out_size, void* d_ws, size_t ws_size,
                              hipStream_t stream)
{
  const float* x   = (const float*)d_in[0];
  const float* ew1 = (const float*)d_in[1];  const float* eb1 = (const float*)d_in[2];
  const float* ew2 = (const float*)d_in[3];  const float* eb2 = (const float*)d_in[4];
  const float* ew3 = (const float*)d_in[5];  const float* eb3 = (const float*)d_in[6];
  const float* zw  = (const float*)d_in[7];  const float* zb  = (const float*)d_in[8];
  const float* dw1 = (const float*)d_in[9];  const float* db1 = (const float*)d_in[10];
  const float* dw2 = (const float*)d_in[11]; const float* db2 = (const float*)d_in[12];
  const float* dw3 = (const float*)d_in[13]; const float* db3 = (const float*)d_in[14];
  const float* xw  = (const float*)d_in[15]; const float* xb  = (const float*)d_in[16];
  const float* g1  = (const float*)d_in[17];
  const float* g2  = (const float*)d_in[18];
  const float* g3  = (const float*)d_in[19];
  const float* g4  = (const float*)d_in[20];
  const float* g5  = (const float*)d_in[21];
  const float* m1w = (const float*)d_in[22]; const float* m1b = (const float*)d_in[23];
  const float* m2w = (const float*)d_in[24]; const float* m2b = (const float*)d_in[25];
  const float* m3w = (const float*)d_in[26]; const float* m3b = (const float*)d_in[27];
  const float* mlw = (const float*)d_in[28]; const float* mlb = (const float*)d_in[29];
  const float* cluster = (const float*)d_in[30];
  const int* src = (const int*)d_in[31];
  const int* dst = (const int*)d_in[32];

  const int NI=2000, H1=500, H2=500, H3=2000;
  const int N = in_sizes[0] / NI;      // 20000
  const int E = in_sizes[31];          // 320000
  const int M_tot = E + N;
  const int Mp = ((N + 127)/128)*128;  // 20096

  float* out = (float*)d_out;
  float* out_xbar = out;
  float* out_q    = out + (size_t)N*NI;
  float* out_pred = out_q + (size_t)N*10;
  float* out_p    = out_pred + (size_t)N*10;

  // ---- workspace carve ----
  char* base = (char*)d_ws;
  size_t off = 0;
  auto AF = [&](size_t e)->float*{ float* r=(float*)(base+off); off += ((e*sizeof(float)+15)&~(size_t)15); return r; };
  auto AI = [&](size_t e)->int*  { int*   r=(int*)  (base+off); off += ((e*sizeof(int)  +15)&~(size_t)15); return r; };
  auto AH = [&](size_t e)->_Float16*{ _Float16* r=(_Float16*)(base+off); off += ((e*sizeof(_Float16)+15)&~(size_t)15); return r; };

  int* deg_out = AI(N); int* deg_in = AI(N);
  int* rp = AI(N+1); int* cursor = AI(N); int* ci = AI(M_tot);
  float* nsrc = AF(N); float* ndst = AF(N); float* colsum = AF(16);
  float* zlat = AF((size_t)N*10);
  float* pre4 = AF((size_t)N*10);
  float* pre5 = AF((size_t)N*10);
  float* hbuf = AF((size_t)N*10);
  float* Ybuf = AF((size_t)Mp*128);       // 2 split-K halves of [Mp x 64]
  // fp16 buffers
  _Float16* xh    = AH((size_t)Mp*2048);  // x_h -> z3_h -> dh1_h
  _Float16* tra3h = AH((size_t)Mp*2048);
  _Float16* dualh = AH((size_t)Mp*1024);  // cols 0-511 tra1h | cols 512-1023 pre1h
  _Float16* tra2h = AH((size_t)Mp*512);
  _Float16* z1h   = AH((size_t)Mp*512);
  _Float16* z2h   = AH((size_t)Mp*512);
  _Float16* Ph    = AH((size_t)Mp*512);   // agg2_h -> agg3_h -> dh3_h
  _Float16* Qh    = AH((size_t)Mp*512);   // mix1_h -> mix2_h -> dh2_h
  _Float16* z4zh  = AH((size_t)Mp*64);
  _Float16* wch   = AH((size_t)128*3136);
  _Float16* ewg1h = AH((size_t)1024*2048);
  _Float16* ew1h  = ewg1h;
  _Float16* g1h   = ewg1h + (size_t)512*2048;
  _Float16* ew2h = AH((size_t)512*512);
  _Float16* ew3h = AH((size_t)2048*512);
  _Float16* dw2h = AH((size_t)512*2048);
  _Float16* dw3h = AH((size_t)512*512);
  _Float16* xwh  = AH((size_t)2048*512);
  _Float16* g2h  = AH((size_t)512*512);
  _Float16* g3h  = AH((size_t)2048*512);
  (void)ws_size; (void)out_size; (void)n_in;

  dim3 b256(256);
  // ---- graph build ----
  k_ginit<<<(N+255)/256, b256, 0, stream>>>(deg_out, deg_in, cursor, colsum, N);
  k_count<<<(E+255)/256, b256, 0, stream>>>(src, dst, deg_out, deg_in, E);
  k_scan<<<1, 1024, 0, stream>>>(deg_in, rp, N);
  k_fill<<<(M_tot+255)/256, b256, 0, stream>>>(src, dst, rp, cursor, ci, E, N);
  k_norms<<<(N+255)/256, b256, 0, stream>>>(deg_out, deg_in, nsrc, ndst, N);

  // ---- conversions ----
  {
    long tot = (long)Mp*(2048/8);
    k_conv_a<<<(tot+255)/256, b256, 0, stream>>>(x, xh, N, NI, Mp, 2048);
  }
  {
    ConvPack cp; int nt = 0, nd = 0;
    auto add2 = [&](const float* in_, int K_, int N_, int Np_, int Kp_, _Float16* o_){
      cp.d[nd] = {in_, o_, K_, N_, Np_, Kp_};
      cp.tile0[nd] = nt; nt += (Kp_/32)*(Np_/32); ++nd;
    };
    add2(ew1, 2000, 500, 512, 2048, ew1h);
    add2(g1,  2000, 500, 512, 2048, g1h);
    add2(ew2, 500, 500, 512, 512, ew2h);
    add2(ew3, 500, 2000, 2048, 512, ew3h);
    add2(dw2, 2000, 500, 512, 2048, dw2h);
    add2(dw3, 500, 500, 512, 512, dw3h);
    add2(xw,  500, 2000, 2048, 512, xwh);
    add2(g2,  500, 500, 512, 512, g2h);
    add2(g3,  500, 2000, 2048, 512, g3h);
    cp.tile0[9] = nt;
    k_conv_bt_all<<<nt, b256, 0, stream>>>(cp);
  }
  k_build_wc<<<(128*3136+255)/256, b256, 0, stream>>>(mlw, g5, wch);

  const int MT = Mp/128;   // 157
  #define HGEMM(ACT,BIAS, A_,BT_,BIASP_,CH_, NV_,NP_,KP_,LDA_) \
    k_hgemm<ACT,BIAS><<<dim3((NP_)/128, MT), b256, 0, stream>>>( \
      (A_),(BT_),(BIASP_),(CH_), N, (NV_), (NP_), (KP_), (LDA_))

  // ---- encoder + first GCN layer fused on the x pass ----
  k_hgemm_dual<<<dim3(8, MT), b256, 0, stream>>>(xh, ewg1h, eb1, dualh, N);                // tra1h|pre1h
  HGEMM(1,true,  dualh, ew2h, eb2, tra2h, 500, 512, 512, 1024);                            // tra2h
  HGEMM(1,true,  tra2h, ew3h, eb3, tra3h, 2000, 2048, 512, 512);                           // tra3h
  k_skinny10_h<<<512, b256, 0, stream>>>(tra3h, 2048, zw, 2000, zb, zlat, N, 0);           // zlat
  k_tailz<<<(N*54+255)/256, b256, 0, stream>>>(zlat, z4zh, N);                             // z4zh cols 10-63

  // ---- GCN branch ----
  k_spmm2<2><<<N, b256, 0, stream>>>(dualh+512, 1024, rp, ci, nsrc, ndst, z1h, H1, 512);   // z1h (leaky)
  k_gate_mix_w<<<(N+3)/4, b256, 0, stream>>>(dualh, 1024, z1h, 512, m1w, m1b, Qh, H1, 512, N); // mix1h
  k_spmm2<0><<<N, b256, 0, stream>>>(Qh, 512, rp, ci, nsrc, ndst, Ph, H1, 512);            // agg2h
  HGEMM(2,false, Ph, g2h, nullptr, z2h, 500, 512, 512, 512);                               // z2h (leaky)
  k_gate_mix_w<<<(N+3)/4, b256, 0, stream>>>(tra2h, 512, z2h, 512, m2w, m2b, Qh, H2, 512, N);  // mix2h
  k_spmm2<0><<<N, b256, 0, stream>>>(Qh, 512, rp, ci, nsrc, ndst, Ph, H2, 512);            // agg3h
  HGEMM(2,false, Ph, g3h, nullptr, xh, 2000, 2048, 512, 512);                              // z3h (xh slot)
  k_fused3<<<512, b256, 0, stream>>>(tra3h, xh, m3w, m3b, g4, pre4, N);                    // gate3 + mix@g4
  k_spmm10z4<<<(N*10+255)/256, b256, 0, stream>>>(pre4, rp, ci, nsrc, ndst, z4zh, N);      // z4 -> z4zh[0:10]
  k_hgemm_up5<<<dim3(2, MT), b256, 0, stream>>>(z1h, z2h, xh, z4zh, wch, Ybuf, N, Mp);
  k_up5_fin<<<(N+255)/256, b256, 0, stream>>>(Ybuf, mlb, pre5, N, Mp);
  k_spmm10<0><<<(N*10+255)/256, b256, 0, stream>>>(pre5, rp, ci, nsrc, ndst, hbuf, N);
  k_softmax10<<<(N+255)/256, b256, 0, stream>>>(hbuf, out_pred, N);
  // ---- clustering head ----
  k_q<<<(N+255)/256, b256, 0, stream>>>(zlat, cluster, out_q, colsum, N);
  k_p<<<(N+255)/256, b256, 0, stream>>>(out_q, colsum, out_p, N);

  // ---- decoder (xh/z3h dead after up5 GEMM) ----
  k_broad_reg<<<512, 512, 0, stream>>>(zlat, dw1, db1, xh, N, Mp, H3, 2048);               // dh1h
  HGEMM(1,true,  xh, dw2h, db2, Qh, 500, 512, 2048, 2048);                                 // dh2h
  HGEMM(1,true,  Qh, dw3h, db3, Ph, 500, 512, 512, 512);                                   // dh3h
  k_hgemm_f32t<<<dim3(16, MT), b256, 0, stream>>>(Ph, xwh, xb, out_xbar, N, 2000, 512, 512); // x_bar
  #undef HGEMM
}

// Round 14
// 1389.475 us; speedup vs baseline: 1.0450x; 1.0450x over previous
//
#include <hip/hip_runtime.h>
#include <cstdint>

typedef _Float16 half8 __attribute__((ext_vector_type(8)));
typedef _Float16 h2f __attribute__((ext_vector_type(2)));
typedef float f32x4 __attribute__((ext_vector_type(4)));

__device__ __forceinline__ float leakyf(float v){ return v > 0.f ? v : 0.01f*v; }
__device__ __forceinline__ float actf(float v, int act){
  if (act == 1) return fmaxf(v, 0.f);
  if (act == 2) return leakyf(v);
  return v;
}
__device__ __forceinline__ unsigned pkh(float a, float b){
  h2f p; p[0]=(_Float16)a; p[1]=(_Float16)b; return __builtin_bit_cast(unsigned, p);
}
__device__ __forceinline__ h2f uph(unsigned u){ return __builtin_bit_cast(h2f, u); }

__device__ __forceinline__ void gl_lds16(const void* g, void* l){
  __builtin_amdgcn_global_load_lds((const __attribute__((address_space(1))) void*)g,
                                   (__attribute__((address_space(3))) void*)l, 16, 0, 0);
}

// stage one 128x64(half) tile (16KB) into LDS, row-major with XOR chunk swizzle.
// physical byte = row*128 + pchunk*16; content = global chunk (pchunk ^ (row&7)).
__device__ __forceinline__ void stage64(const _Float16* __restrict__ g, long ld,
                                        int r0, long k0, _Float16* lbuf, int tid){
  #pragma unroll
  for (int i=0;i<4;++i){
    int gidx = i*256 + tid;
    int row = gidx >> 3, pc = gidx & 7;
    int lc = pc ^ (row & 7);
    gl_lds16(g + (size_t)(r0+row)*ld + k0 + lc*8, (char*)lbuf + i*4096 + (size_t)tid*16);
  }
}

// bijective XCD-chunked swizzle (m204)
__device__ __forceinline__ void xcd_swz(int& bx, int& by){
  int nx = gridDim.x;
  int nwg = nx * gridDim.y;
  int lid = blockIdx.y*nx + blockIdx.x;
  int q = nwg >> 3, r = nwg & 7;
  int xcd = lid & 7, idx = lid >> 3;
  int w = (xcd < r ? xcd*(q+1) : r*(q+1) + (xcd-r)*q) + idx;
  bx = w % nx; by = w / nx;
}

// ---------------- graph build ----------------
__global__ void k_ginit(int* deg_out, int* deg_in, int* cursor, float* colsum, int n){
  int i = blockIdx.x*blockDim.x + threadIdx.x;
  if (i < n){ deg_out[i] = 1; deg_in[i] = 1; cursor[i] = 0; }
  if (i < 16) colsum[i] = 0.f;
}
__global__ void k_count(const int* __restrict__ src, const int* __restrict__ dst,
                        int* deg_out, int* deg_in, int e){
  int i = blockIdx.x*blockDim.x + threadIdx.x;
  if (i < e){ atomicAdd(&deg_out[src[i]], 1); atomicAdd(&deg_in[dst[i]], 1); }
}
__global__ void k_scan(const int* __restrict__ deg, int* rp, int n){
  __shared__ int sums[1024];
  int t = threadIdx.x;
  int per = (n + 1023)/1024;
  int base = t*per;
  int s = 0;
  for (int i = 0; i < per; ++i){ int j = base+i; if (j < n) s += deg[j]; }
  sums[t] = s; __syncthreads();
  for (int off = 1; off < 1024; off <<= 1){
    int v = 0;
    if (t >= off) v = sums[t-off];
    __syncthreads();
    if (t >= off) sums[t] += v;
    __syncthreads();
  }
  int run = (t == 0) ? 0 : sums[t-1];
  for (int i = 0; i < per; ++i){ int j = base+i; if (j < n){ rp[j] = run; run += deg[j]; } }
  if (t == 1023) rp[n] = sums[1023];
}
__global__ void k_fill(const int* __restrict__ src, const int* __restrict__ dst,
                       const int* __restrict__ rp, int* cursor, int* ci, int e, int n){
  int i = blockIdx.x*blockDim.x + threadIdx.x;
  if (i >= e + n) return;
  int s, d;
  if (i < e){ s = src[i]; d = dst[i]; } else { s = d = i - e; }
  int pos = atomicAdd(&cursor[d], 1);
  ci[rp[d] + pos] = s;
}
__global__ void k_norms(const int* deg_out, const int* deg_in, float* nsrc, float* ndst, int n){
  int i = blockIdx.x*blockDim.x + threadIdx.x;
  if (i < n){ nsrc[i] = rsqrtf((float)deg_out[i]); ndst[i] = rsqrtf((float)deg_in[i]); }
}

// ---------------- conversions ----------------
__global__ void k_conv_a(const float* __restrict__ in, _Float16* __restrict__ out,
                         int M, int K, int Mp, int Kp){
  long idx = (long)blockIdx.x*blockDim.x + threadIdx.x;
  long total = (long)Mp*(Kp/8);
  if (idx >= total) return;
  int kp8 = Kp/8;
  int m = (int)(idx / kp8);
  int k8 = (int)(idx % kp8) * 8;
  half8 o;
  #pragma unroll
  for (int j=0;j<8;++j){
    int k = k8+j;
    o[j] = (_Float16)((m<M && k<K) ? in[(size_t)m*K + k] : 0.f);
  }
  *(half8*)&out[(size_t)m*Kp + k8] = o;
}

// batched transpose-convert: 9 weight matrices in one launch
struct ConvDesc { const float* in; _Float16* out; int K, N, Np, Kp; };
struct ConvPack { ConvDesc d[9]; int tile0[10]; };
__global__ __launch_bounds__(256) void k_conv_bt_all(ConvPack p){
  __shared__ float t[32][33];
  int tile = blockIdx.x;
  int di = 0;
  while (di < 8 && tile >= p.tile0[di+1]) ++di;
  ConvDesc d = p.d[di];
  int lt = tile - p.tile0[di];
  int ntx = d.Kp/32;
  int kb = (lt % ntx)*32, nb = (lt / ntx)*32;
  int tx = threadIdx.x & 31, ty = threadIdx.x >> 5;
  for (int r=ty; r<32; r+=8){
    int k = kb+r, n = nb+tx;
    t[r][tx] = (k<d.K && n<d.N) ? d.in[(size_t)k*d.N+n] : 0.f;
  }
  __syncthreads();
  for (int r=ty; r<32; r+=8){
    int n = nb+r, k = kb+tx;
    if (n<d.Np && k<d.Kp) d.out[(size_t)n*d.Kp+k] = (_Float16)t[tx][r];
  }
}

// build Wc [128 x 3136] fp16: packed mlw + block-diag g5 over padded segment layout
__global__ void k_build_wc(const float* __restrict__ mlw, const float* __restrict__ g5,
                           _Float16* __restrict__ wc){
  int idx = blockIdx.x*blockDim.x + threadIdx.x;
  if (idx >= 128*3136) return;
  int c = idx / 3136, k = idx - (idx/3136)*3136;
  int seg = -1, real_k = 0;
  if (k < 512){ if (k < 500){ seg=0; real_k=k; } }
  else if (k < 1024){ int kk=k-512; if (kk<500){ seg=1; real_k=500+kk; } }
  else if (k < 3072){ int kk=k-1024; if (kk<2000){ seg=2; real_k=1000+kk; } }
  else { int kk=k-3072; if (kk<10){ seg=3; real_k=3000+kk; } else if (kk<20){ seg=4; real_k=3010+kk-10; } }
  float val = 0.f;
  if (seg >= 0){
    if (c < 5) val = mlw[(size_t)real_k*5 + c];
    else if (c < 55){ int t=c-5; if (t/10 == seg) val = g5[(size_t)real_k*10 + (t-(t/10)*10)]; }
  }
  wc[(size_t)c*3136 + k] = (_Float16)val;
}

// fragment read + MFMA for BK=64 swizzled tile
#define MFMA_K64(BUF_A, BUF_B) \
  _Pragma("unroll") \
  for (int kk=0; kk<2; ++kk){ \
    half8 af[4], bf[4]; \
    _Pragma("unroll") \
    for (int mi=0;mi<4;++mi){ \
      int R = wr*64 + mi*16 + (l&15); \
      int p = (kk*4 + (l>>4)) ^ (R&7); \
      af[mi] = *(const half8*)&(BUF_A)[R*64 + p*8]; \
    } \
    _Pragma("unroll") \
    for (int nj=0;nj<4;++nj){ \
      int R = wc*64 + nj*16 + (l&15); \
      int p = (kk*4 + (l>>4)) ^ (R&7); \
      bf[nj] = *(const half8*)&(BUF_B)[R*64 + p*8]; \
    } \
    _Pragma("unroll") \
    for (int mi=0;mi<4;++mi) \
      _Pragma("unroll") \
      for (int nj=0;nj<4;++nj) \
        acc[mi][nj] = __builtin_amdgcn_mfma_f32_16x16x32_f16(af[mi], bf[nj], acc[mi][nj], 0,0,0); \
  }

// ---------------- fp16 MFMA GEMM: Ch = act(A @ B^T + bias), fp16 out ----------------
template<int ACT, bool BIAS>
__global__ __launch_bounds__(256) void k_hgemm(
    const _Float16* __restrict__ A, const _Float16* __restrict__ BT,
    const float* __restrict__ bias, _Float16* __restrict__ Ch,
    int M, int Nvalid, long Np, long Kp, long lda)
{
  __shared__ __align__(16) _Float16 Asm[8192];
  __shared__ __align__(16) _Float16 Bsm[8192];
  int bx, by; xcd_swz(bx, by);
  const int m0 = by*128, n0 = bx*128;
  const int tid = threadIdx.x;
  const int l = tid & 63, w = tid >> 6;
  const int wr = w >> 1, wc = w & 1;
  f32x4 acc[4][4] = {};

  for (long k0 = 0; k0 < Kp; k0 += 64){
    stage64(A,  lda, m0, k0, Asm, tid);
    stage64(BT, Kp,  n0, k0, Bsm, tid);
    __syncthreads();
    MFMA_K64(Asm, Bsm)
    __syncthreads();
  }

  const int cr = (l>>4)*4, cc = l&15;
  #pragma unroll
  for (int mi=0;mi<4;++mi){
    #pragma unroll
    for (int nj=0;nj<4;++nj){
      int cbase = n0 + wc*64 + nj*16 + cc;
      bool cvalid = cbase < Nvalid;
      #pragma unroll
      for (int q=0;q<4;++q){
        int r = m0 + wr*64 + mi*16 + cr + q;
        float v = acc[mi][nj][q];
        if (BIAS && cvalid) v += bias[cbase];
        if (ACT==1) v = fmaxf(v,0.f); else if (ACT==2) v = leakyf(v);
        if (!cvalid) v = 0.f;
        Ch[(size_t)r*Np + cbase] = (_Float16)(r < M ? v : 0.f);
      }
    }
  }
}

// ---------------- dual GEMM: cols 0-511 = relu(x@ew1+eb1), cols 512-1023 = x@g1 ----------------
__global__ __launch_bounds__(256) void k_hgemm_dual(
    const _Float16* __restrict__ A, const _Float16* __restrict__ BT,
    const float* __restrict__ eb1, _Float16* __restrict__ Ch, int M)
{
  const long Kp = 2048;
  __shared__ __align__(16) _Float16 Asm[8192];
  __shared__ __align__(16) _Float16 Bsm[8192];
  int bx, by; xcd_swz(bx, by);
  const int m0 = by*128, n0 = bx*128;
  const int tid = threadIdx.x;
  const int l = tid & 63, w = tid >> 6;
  const int wr = w >> 1, wc = w & 1;
  f32x4 acc[4][4] = {};

  for (long k0 = 0; k0 < Kp; k0 += 64){
    stage64(A,  Kp, m0, k0, Asm, tid);
    stage64(BT, Kp, n0, k0, Bsm, tid);
    __syncthreads();
    MFMA_K64(Asm, Bsm)
    __syncthreads();
  }

  const int cr = (l>>4)*4, cc = l&15;
  #pragma unroll
  for (int mi=0;mi<4;++mi){
    #pragma unroll
    for (int nj=0;nj<4;++nj){
      int cbase = n0 + wc*64 + nj*16 + cc;
      bool hi = cbase >= 512;
      int cl = hi ? cbase - 512 : cbase;
      bool cvalid = cl < 500;
      #pragma unroll
      for (int q=0;q<4;++q){
        int r = m0 + wr*64 + mi*16 + cr + q;
        float v = acc[mi][nj][q];
        if (!hi && cvalid){ v += eb1[cl]; v = fmaxf(v, 0.f); }
        if (!cvalid) v = 0.f;
        Ch[(size_t)r*1024 + cbase] = (_Float16)(r < M ? v : 0.f);
      }
    }
  }
}

// ---------------- f32-out GEMM with LDS-transposed coalesced epilogue (x_bar) ----------------
__global__ __launch_bounds__(256) void k_hgemm_f32t(
    const _Float16* __restrict__ A, const _Float16* __restrict__ BT,
    const float* __restrict__ bias, float* __restrict__ C,
    int M, int Nvalid, long Kp, long lda)
{
  __shared__ __align__(16) _Float16 Asm[8192];
  __shared__ __align__(16) _Float16 Bsm[8192];
  __shared__ __align__(16) float scr[16*128];
  int bx, by; xcd_swz(bx, by);
  const int m0 = by*128, n0 = bx*128;
  const int tid = threadIdx.x;
  const int l = tid & 63, w = tid >> 6;
  const int wr = w >> 1, wc = w & 1;
  f32x4 acc[4][4] = {};

  for (long k0 = 0; k0 < Kp; k0 += 64){
    stage64(A,  lda, m0, k0, Asm, tid);
    stage64(BT, Kp,  n0, k0, Bsm, tid);
    __syncthreads();
    MFMA_K64(Asm, Bsm)
    __syncthreads();
  }

  const int cr = (l>>4)*4, cc = l&15;
  for (int p = 0; p < 8; ++p){
    if (wr == (p>>2)){
      int mi = p & 3;
      #pragma unroll
      for (int nj=0;nj<4;++nj){
        int cb = wc*64 + nj*16 + cc;
        float bv = (n0+cb < Nvalid) ? bias[n0+cb] : 0.f;
        #pragma unroll
        for (int q=0;q<4;++q)
          scr[(cr+q)*128 + cb] = acc[mi][nj][q] + bv;
      }
    }
    __syncthreads();
    #pragma unroll
    for (int j=0;j<2;++j){
      int flat = (tid + j*256)*4;
      int rl = flat >> 7, col = flat & 127;
      int r = m0 + p*16 + rl;
      int cb = n0 + col;
      if (r < M && cb < Nvalid)
        *(f32x4*)&C[(size_t)r*Nvalid + cb] = *(const f32x4*)&scr[flat];
    }
    __syncthreads();
  }
}

// ---------------- up5 GEMM, split-K x2 (1536 + 1600): Y[half][Mp x 64] ----------------
__global__ __launch_bounds__(256) void k_hgemm_up5(
    const _Float16* __restrict__ z1h, const _Float16* __restrict__ z2h,
    const _Float16* __restrict__ z3h, const _Float16* __restrict__ z4zh,
    const _Float16* __restrict__ Wc, float* __restrict__ Y, int M, int Mp)
{
  __shared__ __align__(16) _Float16 Asm[8192];
  __shared__ __align__(16) _Float16 Bsm[8192];
  int bx, by; xcd_swz(bx, by);   // bx in {0,1}: K-half
  const int m0 = by*128;
  const int tid = threadIdx.x;
  const int l = tid & 63, w = tid >> 6;
  const int wr = w >> 1, wc = w & 1;
  f32x4 acc[4][4] = {};

  auto stage_a = [&](int k0, _Float16* lbuf){
    const _Float16* ab; long astr; int kk;
    if (k0 < 512){ ab=z1h; astr=512; kk=k0; }
    else if (k0 < 1024){ ab=z2h; astr=512; kk=k0-512; }
    else if (k0 < 3072){ ab=z3h; astr=2048; kk=k0-1024; }
    else { ab=z4zh; astr=64; kk=k0-3072; }
    stage64(ab, astr, m0, kk, lbuf, tid);
  };

  const int kbase = bx*1536;
  const int ntl = bx ? 25 : 24;
  for (int t = 0; t < ntl; ++t){
    int k0 = kbase + t*64;
    stage_a(k0, Asm);
    stage64(Wc, 3136, 0, k0, Bsm, tid);
    __syncthreads();
    MFMA_K64(Asm, Bsm)
    __syncthreads();
  }

  float* Yh = Y + (size_t)bx*Mp*64;
  const int cr = (l>>4)*4, cc = l&15;
  #pragma unroll
  for (int mi=0;mi<4;++mi){
    #pragma unroll
    for (int nj=0;nj<4;++nj){
      int cbase = wc*64 + nj*16 + cc;
      if (cbase >= 64) continue;
      #pragma unroll
      for (int q=0;q<4;++q){
        int r = m0 + wr*64 + mi*16 + cr + q;
        if (r < M) Yh[(size_t)r*64 + cbase] = acc[mi][nj][q];
      }
    }
  }
}

// epilogue: sum split-K halves; u = l2(softmax(leaky(logits+mlb))); pre5 = sum_i u_i*P_i
__global__ void k_up5_fin(const float* __restrict__ Y, const float* __restrict__ mlb,
                          float* __restrict__ pre5, int M, int Mp){
  int row = blockIdx.x*blockDim.x + threadIdx.x;
  if (row >= M) return;
  const float* y0 = Y + (size_t)row*64;
  const float* y1 = Y + (size_t)Mp*64 + (size_t)row*64;
  float y[64];
  #pragma unroll
  for (int c=0;c<55;++c) y[c] = y0[c] + y1[c];
  float v[5]; float mx = -1e30f;
  #pragma unroll
  for (int c=0;c<5;++c){ float t = leakyf(y[c] + mlb[c]); v[c]=t; mx=fmaxf(mx,t); }
  float ss=0.f;
  #pragma unroll
  for (int c=0;c<5;++c){ v[c]=expf(v[c]-mx); ss += v[c]*v[c]; }
  float inv = rsqrtf(fmaxf(ss,1e-30f));
  #pragma unroll
  for (int c=0;c<5;++c) v[c] *= inv;
  #pragma unroll
  for (int c=0;c<10;++c){
    float s = 0.f;
    #pragma unroll
    for (int i=0;i<5;++i) s += v[i]*y[5 + 10*i + c];
    pre5[(size_t)row*10 + c] = s;
  }
}

// tail: z4zh[row][0:10]=z4, [10:20]=zlat, rest 0
__global__ void k_tail64(const float* __restrict__ z4, const float* __restrict__ zlat,
                         _Float16* __restrict__ z4zh, int M){
  int idx = blockIdx.x*blockDim.x + threadIdx.x;
  if (idx >= M*64) return;
  int row = idx >> 6, j = idx & 63;
  float v = 0.f;
  if (j < 10) v = z4[(size_t)row*10 + j];
  else if (j < 20) v = zlat[(size_t)row*10 + j - 10];
  z4zh[idx] = (_Float16)v;
}

// ---------------- skinny 10-out GEMM, fp16 A, LDS-staged transposed f32 weights ----------------
__global__ __launch_bounds__(256) void k_skinny10_h(
    const _Float16* __restrict__ A, long lda, const float* __restrict__ W, int K,
    const float* __restrict__ bias, float* __restrict__ out, int M, int act)
{
  __shared__ float wl[10*2000];
  int tid = threadIdx.x;
  for (int idx = tid; idx < K*10; idx += 256){
    int k = idx/10, c = idx - k*10;
    wl[c*K + k] = W[idx];
  }
  __syncthreads();
  int wv = tid >> 6, lane = tid & 63;
  int stride = gridDim.x*4;
  for (int row = blockIdx.x*4 + wv; row < M; row += stride){
    const _Float16* a = A + (size_t)row*lda;
    float acc[10];
    #pragma unroll
    for (int c=0;c<10;++c) acc[c]=0.f;
    for (int k0 = lane*2; k0 < K; k0 += 128){
      h2f t2 = *(const h2f*)(a + k0);
      float v0 = (float)t2[0], v1 = (float)t2[1];
      #pragma unroll
      for (int c=0;c<10;++c) acc[c] += v0*wl[c*K + k0] + v1*wl[c*K + k0 + 1];
    }
    #pragma unroll
    for (int c=0;c<10;++c){
      #pragma unroll
      for (int off=32; off; off>>=1) acc[c] += __shfl_down(acc[c], off);
    }
    if (lane == 0){
      #pragma unroll
      for (int c=0;c<10;++c){
        float v = acc[c] + (bias ? bias[c] : 0.f);
        out[(size_t)row*10 + c] = actf(v, act);
      }
    }
  }
}

// ---------------- fused gate3 + mix3@g4 ----------------
__global__ __launch_bounds__(256) void k_fused3(
    const _Float16* __restrict__ tra, const _Float16* __restrict__ zin,
    const float* __restrict__ m3w, const float* __restrict__ b3,
    const float* __restrict__ g4, float* __restrict__ pre4, int M)
{
  const int K = 2000;
  __shared__ unsigned g4l[5*2000];
  __shared__ unsigned mt01[2000];
  __shared__ unsigned mz01[2000];
  int tid = threadIdx.x;
  for (int k = tid; k < K; k += 256){
    mt01[k] = pkh(m3w[2*k],       m3w[2*k+1]);
    mz01[k] = pkh(m3w[2*(K+k)],   m3w[2*(K+k)+1]);
  }
  for (int idx = tid; idx < K*5; idx += 256){
    int jp = idx / K, k = idx - jp*K;
    g4l[idx] = pkh(g4[(size_t)k*10 + 2*jp], g4[(size_t)k*10 + 2*jp + 1]);
  }
  __syncthreads();
  int wv = tid >> 6, lane = tid & 63;
  int stride = gridDim.x*4;
  for (int row = blockIdx.x*4 + wv; row < M; row += stride){
    const _Float16* tr = tra + (size_t)row*2048;
    const _Float16* zr = zin + (size_t)row*2048;
    float a0=0.f, a1=0.f;
    float t4[10], z4a[10];
    #pragma unroll
    for (int c=0;c<10;++c){ t4[c]=0.f; z4a[c]=0.f; }
    for (int k0 = lane*2; k0 < K; k0 += 128){
      h2f t2 = *(const h2f*)(tr + k0);
      h2f z2 = *(const h2f*)(zr + k0);
      #pragma unroll
      for (int j=0;j<2;++j){
        int k = k0 + j;
        float t = (float)t2[j], z = (float)z2[j];
        h2f mt = uph(mt01[k]); h2f mz = uph(mz01[k]);
        a0 += t*(float)mt[0] + z*(float)mz[0];
        a1 += t*(float)mt[1] + z*(float)mz[1];
        #pragma unroll
        for (int jp=0;jp<5;++jp){
          h2f p = uph(g4l[jp*K + k]);
          float p0 = (float)p[0], p1 = (float)p[1];
          t4[2*jp]   += t*p0;  t4[2*jp+1]  += t*p1;
          z4a[2*jp]  += z*p0;  z4a[2*jp+1] += z*p1;
        }
      }
    }
    #pragma unroll
    for (int off=32; off; off>>=1){
      a0 += __shfl_down(a0,off); a1 += __shfl_down(a1,off);
      #pragma unroll
      for (int c=0;c<10;++c){
        t4[c]  += __shfl_down(t4[c], off);
        z4a[c] += __shfl_down(z4a[c], off);
      }
    }
    if (lane == 0){
      float s0 = leakyf(a0 + b3[0]);
      float s1 = leakyf(a1 + b3[1]);
      float mx = fmaxf(s0, s1);
      float e0 = expf(s0-mx), e1 = expf(s1-mx);
      float inv = rsqrtf(fmaxf(e0*e0 + e1*e1, 1e-30f));
      float mzc = e0*inv, mtc = e1*inv;
      #pragma unroll
      for (int c=0;c<10;++c)
        pre4[(size_t)row*10 + c] = mzc*z4a[c] + mtc*t4[c];
    }
  }
}

// ---------------- fused gate+mix, fp16 in/out ----------------
__global__ void k_gate_mix_hh(const _Float16* __restrict__ tra, long Wpa,
                              const _Float16* __restrict__ zin, long Wpz,
                              const float* __restrict__ w, const float* __restrict__ b,
                              _Float16* __restrict__ mix, int W, long Wpo)
{
  int row = blockIdx.x;
  int tid = threadIdx.x;
  const _Float16* tr = tra + (size_t)row*Wpa;
  const _Float16* zr = zin + (size_t)row*Wpz;
  int c = tid*2;
  h2f t2 = *(const h2f*)(tr + c);
  h2f z2 = *(const h2f*)(zr + c);
  float a0=0.f, a1=0.f;
  #pragma unroll
  for (int j=0;j<2;++j){
    int k = c + j;
    if (k < W){
      float t = (float)t2[j], zv = (float)z2[j];
      a0 += t*w[2*k]   + zv*w[2*(W+k)];
      a1 += t*w[2*k+1] + zv*w[2*(W+k)+1];
    }
  }
  #pragma unroll
  for (int off=32; off; off>>=1){ a0 += __shfl_down(a0,off); a1 += __shfl_down(a1,off); }
  __shared__ float red0[4], red1[4], m01[2];
  int wv = tid>>6, ln = tid&63;
  if (ln==0){ red0[wv]=a0; red1[wv]=a1; }
  __syncthreads();
  if (tid==0){
    float s0 = red0[0]+red0[1]+red0[2]+red0[3] + b[0];
    float s1 = red1[0]+red1[1]+red1[2]+red1[3] + b[1];
    s0 = leakyf(s0); s1 = leakyf(s1);
    float mx = fmaxf(s0,s1);
    float e0 = expf(s0-mx), e1 = expf(s1-mx);
    float inv = rsqrtf(fmaxf(e0*e0+e1*e1, 1e-30f));
    m01[0] = e0*inv; m01[1] = e1*inv;
  }
  __syncthreads();
  float mz = m01[0], mt = m01[1];
  h2f o;
  #pragma unroll
  for (int j=0;j<2;++j){
    int k = c + j;
    o[j] = (_Float16)(k < W ? (mz*(float)z2[j] + mt*(float)t2[j]) : 0.f);
  }
  *(h2f*)(mix + (size_t)row*Wpo + c) = o;
}

// ---------------- SpMM gather, fp16x2 loads, 4-edge unrolled; fp16 out ----------------
template<int ACT>
__global__ void k_spmm2(const _Float16* __restrict__ h, long Wpi, const int* __restrict__ rp,
                        const int* __restrict__ ci, const float* __restrict__ nsrc,
                        const float* __restrict__ ndst, _Float16* __restrict__ outh,
                        int W, long Wpo)
{
  int row = blockIdx.x;
  int tid = threadIdx.x;
  int c = tid*2;
  int e0 = rp[row], e1 = rp[row+1];
  float a0=0.f, a1=0.f;
  int e = e0;
  for (; e+4 <= e1; e+=4){
    int s0=ci[e], s1=ci[e+1], s2=ci[e+2], s3=ci[e+3];
    float w0=nsrc[s0], w1=nsrc[s1], w2=nsrc[s2], w3=nsrc[s3];
    h2f p0 = *(const h2f*)(h + (size_t)s0*Wpi + c);
    h2f p1 = *(const h2f*)(h + (size_t)s1*Wpi + c);
    h2f p2 = *(const h2f*)(h + (size_t)s2*Wpi + c);
    h2f p3 = *(const h2f*)(h + (size_t)s3*Wpi + c);
    a0 += w0*(float)p0[0] + w1*(float)p1[0] + w2*(float)p2[0] + w3*(float)p3[0];
    a1 += w0*(float)p0[1] + w1*(float)p1[1] + w2*(float)p2[1] + w3*(float)p3[1];
  }
  for (; e < e1; ++e){
    int s = ci[e];
    float ns = nsrc[s];
    h2f p = *(const h2f*)(h + (size_t)s*Wpi + c);
    a0 += ns*(float)p[0];
    a1 += ns*(float)p[1];
  }
  float nd = ndst[row];
  a0 = actf(a0*nd, ACT); a1 = actf(a1*nd, ACT);
  h2f o;
  o[0] = (_Float16)(c   < W ? a0 : 0.f);
  o[1] = (_Float16)(c+1 < W ? a1 : 0.f);
  *(h2f*)(outh + (size_t)row*Wpo + c) = o;
}

// ---------------- SpMM gather, width 10, 4-edge unrolled ----------------
template<int ACT>
__global__ void k_spmm10(const float* __restrict__ h, const int* __restrict__ rp,
                         const int* __restrict__ ci, const float* __restrict__ nsrc,
                         const float* __restrict__ ndst, float* __restrict__ out, int n)
{
  int idx = blockIdx.x*blockDim.x + threadIdx.x;
  if (idx >= n*10) return;
  int row = idx/10, c = idx - row*10;
  int e0 = rp[row], e1 = rp[row+1];
  float acc = 0.f;
  int e = e0;
  for (; e+4 <= e1; e+=4){
    int s0=ci[e], s1=ci[e+1], s2=ci[e+2], s3=ci[e+3];
    acc += nsrc[s0]*h[(size_t)s0*10 + c] + nsrc[s1]*h[(size_t)s1*10 + c]
         + nsrc[s2]*h[(size_t)s2*10 + c] + nsrc[s3]*h[(size_t)s3*10 + c];
  }
  for (; e < e1; ++e){
    int s = ci[e];
    acc += nsrc[s]*h[(size_t)s*10 + c];
  }
  out[idx] = actf(acc*ndst[row], ACT);
}

// ---------------- decoder layer 1: weights in registers ----------------
__global__ __launch_bounds__(512) void k_broad_reg(
    const float* __restrict__ Z, const float* __restrict__ W, const float* __restrict__ bias,
    _Float16* __restrict__ out, int M, int Mp, int Cc, int Cp)
{
  int tid = threadIdx.x;
  float wr[4][10], bv[4];
  #pragma unroll
  for (int j=0;j<4;++j){
    int c = tid + j*512;
    bool v = c < Cc;
    bv[j] = v ? bias[c] : 0.f;
    #pragma unroll
    for (int q=0;q<10;++q) wr[j][q] = v ? W[(size_t)q*Cc + c] : 0.f;
  }
  for (int row = blockIdx.x; row < Mp; row += gridDim.x){
    float zr[10];
    bool rv = row < M;
    #pragma unroll
    for (int q=0;q<10;++q) zr[q] = rv ? Z[(size_t)row*10 + q] : 0.f;
    #pragma unroll
    for (int j=0;j<4;++j){
      int c = tid + j*512;
      float v = bv[j];
      #pragma unroll
      for (int q=0;q<10;++q) v += zr[q]*wr[j][q];
      v = fmaxf(v, 0.f);
      out[(size_t)row*Cp + c] = (_Float16)((rv && c < Cc) ? v : 0.f);
    }
  }
}

__global__ void k_softmax10(const float* __restrict__ h, float* __restrict__ out, int M){
  int row = blockIdx.x*blockDim.x + threadIdx.x;
  if (row >= M) return;
  float v[10]; float mx=-1e30f;
  #pragma unroll
  for (int j=0;j<10;++j){ v[j]=h[(size_t)row*10+j]; mx=fmaxf(mx,v[j]); }
  float s=0.f;
  #pragma unroll
  for (int j=0;j<10;++j){ v[j]=expf(v[j]-mx); s+=v[j]; }
  float inv=1.f/s;
  #pragma unroll
  for (int j=0;j<10;++j) out[(size_t)row*10+j]=v[j]*inv;
}

__global__ void k_q(const float* __restrict__ z, const float* __restrict__ cluster,
                    float* __restrict__ qout, float* __restrict__ colsum, int M)
{
  __shared__ float part[10];
  if (threadIdx.x < 10) part[threadIdx.x] = 0.f;
  __syncthreads();
  int row = blockIdx.x*blockDim.x + threadIdx.x;
  if (row < M){
    float zr[10];
    #pragma unroll
    for (int j=0;j<10;++j) zr[j] = z[(size_t)row*10+j];
    float qv[10]; float s=0.f;
    #pragma unroll
    for (int k=0;k<10;++k){
      float d2=0.f;
      #pragma unroll
      for (int j=0;j<10;++j){ float t = zr[j]-cluster[k*10+j]; d2 += t*t; }
      float qq = 1.f/(1.f+d2);
      qv[k]=qq; s+=qq;
    }
    float inv = 1.f/s;
    #pragma unroll
    for (int k=0;k<10;++k){
      float val = qv[k]*inv;
      qout[(size_t)row*10+k] = val;
      atomicAdd(&part[k], val);
    }
  }
  __syncthreads();
  if (threadIdx.x < 10) atomicAdd(&colsum[threadIdx.x], part[threadIdx.x]);
}

__global__ void k_p(const float* __restrict__ q, const float* __restrict__ colsum,
                    float* __restrict__ pout, int M){
  int row = blockIdx.x*blockDim.x + threadIdx.x;
  if (row >= M) return;
  float w[10]; float s=0.f;
  #pragma unroll
  for (int k=0;k<10;++k){ float qq=q[(size_t)row*10+k]; float ww=qq*qq/colsum[k]; w[k]=ww; s+=ww; }
  float inv=1.f/s;
  #pragma unroll
  for (int k=0;k<10;++k) pout[(size_t)row*10+k]=w[k]*inv;
}

extern "C" void kernel_launch(void* const* d_in, const int* in_sizes, int n_in,
                              void* d_out, int out_size, void* d_ws, size_t ws_size,
                              hipStream_t stream)
{
  const float* x   = (const float*)d_in[0];
  const float* ew1 = (const float*)d_in[1];  const float* eb1 = (const float*)d_in[2];
  const float* ew2 = (const float*)d_in[3];  const float* eb2 = (const float*)d_in[4];
  const float* ew3 = (const float*)d_in[5];  const float* eb3 = (const float*)d_in[6];
  const float* zw  = (const float*)d_in[7];  const float* zb  = (const float*)d_in[8];
  const float* dw1 = (const float*)d_in[9];  const float* db1 = (const float*)d_in[10];
  const float* dw2 = (const float*)d_in[11]; const float* db2 = (const float*)d_in[12];
  const float* dw3 = (const float*)d_in[13]; const float* db3 = (const float*)d_in[14];
  const float* xw  = (const float*)d_in[15]; const float* xb  = (const float*)d_in[16];
  const float* g1  = (const float*)d_in[17];
  const float* g2  = (const float*)d_in[18];
  const float* g3  = (const float*)d_in[19];
  const float* g4  = (const float*)d_in[20];
  const float* g5  = (const float*)d_in[21];
  const float* m1w = (const float*)d_in[22]; const float* m1b = (const float*)d_in[23];
  const float* m2w = (const float*)d_in[24]; const float* m2b = (const float*)d_in[25];
  const float* m3w = (const float*)d_in[26]; const float* m3b = (const float*)d_in[27];
  const float* mlw = (const float*)d_in[28]; const float* mlb = (const float*)d_in[29];
  const float* cluster = (const float*)d_in[30];
  const int* src = (const int*)d_in[31];
  const int* dst = (const int*)d_in[32];

  const int NI=2000, H1=500, H2=500, H3=2000;
  const int N = in_sizes[0] / NI;      // 20000
  const int E = in_sizes[31];          // 320000
  const int M_tot = E + N;
  const int Mp = ((N + 127)/128)*128;  // 20096

  float* out = (float*)d_out;
  float* out_xbar = out;
  float* out_q    = out + (size_t)N*NI;
  float* out_pred = out_q + (size_t)N*10;
  float* out_p    = out_pred + (size_t)N*10;

  // ---- workspace carve ----
  char* base = (char*)d_ws;
  size_t off = 0;
  auto AF = [&](size_t e)->float*{ float* r=(float*)(base+off); off += ((e*sizeof(float)+15)&~(size_t)15); return r; };
  auto AI = [&](size_t e)->int*  { int*   r=(int*)  (base+off); off += ((e*sizeof(int)  +15)&~(size_t)15); return r; };
  auto AH = [&](size_t e)->_Float16*{ _Float16* r=(_Float16*)(base+off); off += ((e*sizeof(_Float16)+15)&~(size_t)15); return r; };

  int* deg_out = AI(N); int* deg_in = AI(N);
  int* rp = AI(N+1); int* cursor = AI(N); int* ci = AI(M_tot);
  float* nsrc = AF(N); float* ndst = AF(N); float* colsum = AF(16);
  float* zlat = AF((size_t)N*10);
  float* pre4 = AF((size_t)N*10);
  float* z4   = AF((size_t)N*10);
  float* pre5 = AF((size_t)N*10);
  float* hbuf = AF((size_t)N*10);
  float* Ybuf = AF((size_t)Mp*128);       // 2 split-K halves of [Mp x 64]
  // fp16 buffers
  _Float16* xh    = AH((size_t)Mp*2048);  // x_h -> z3_h -> dh1_h
  _Float16* tra3h = AH((size_t)Mp*2048);
  _Float16* dualh = AH((size_t)Mp*1024);  // cols 0-511 tra1h | cols 512-1023 pre1h
  _Float16* tra2h = AH((size_t)Mp*512);
  _Float16* z1h   = AH((size_t)Mp*512);
  _Float16* z2h   = AH((size_t)Mp*512);
  _Float16* Ph    = AH((size_t)Mp*512);   // agg2_h -> agg3_h -> dh3_h
  _Float16* Qh    = AH((size_t)Mp*512);   // mix1_h -> mix2_h -> dh2_h
  _Float16* z4zh  = AH((size_t)Mp*64);
  _Float16* wch   = AH((size_t)128*3136);
  _Float16* ewg1h = AH((size_t)1024*2048);
  _Float16* ew1h  = ewg1h;
  _Float16* g1h   = ewg1h + (size_t)512*2048;
  _Float16* ew2h = AH((size_t)512*512);
  _Float16* ew3h = AH((size_t)2048*512);
  _Float16* dw2h = AH((size_t)512*2048);
  _Float16* dw3h = AH((size_t)512*512);
  _Float16* xwh  = AH((size_t)2048*512);
  _Float16* g2h  = AH((size_t)512*512);
  _Float16* g3h  = AH((size_t)2048*512);
  (void)ws_size; (void)out_size; (void)n_in;

  dim3 b256(256);
  // ---- graph build ----
  k_ginit<<<(N+255)/256, b256, 0, stream>>>(deg_out, deg_in, cursor, colsum, N);
  k_count<<<(E+255)/256, b256, 0, stream>>>(src, dst, deg_out, deg_in, E);
  k_scan<<<1, 1024, 0, stream>>>(deg_in, rp, N);
  k_fill<<<(M_tot+255)/256, b256, 0, stream>>>(src, dst, rp, cursor, ci, E, N);
  k_norms<<<(N+255)/256, b256, 0, stream>>>(deg_out, deg_in, nsrc, ndst, N);

  // ---- conversions ----
  {
    long tot = (long)Mp*(2048/8);
    k_conv_a<<<(tot+255)/256, b256, 0, stream>>>(x, xh, N, NI, Mp, 2048);
  }
  {
    ConvPack cp; int nt = 0, nd = 0;
    auto add2 = [&](const float* in_, int K_, int N_, int Np_, int Kp_, _Float16* o_){
      cp.d[nd] = {in_, o_, K_, N_, Np_, Kp_};
      cp.tile0[nd] = nt; nt += (Kp_/32)*(Np_/32); ++nd;
    };
    add2(ew1, 2000, 500, 512, 2048, ew1h);
    add2(g1,  2000, 500, 512, 2048, g1h);
    add2(ew2, 500, 500, 512, 512, ew2h);
    add2(ew3, 500, 2000, 2048, 512, ew3h);
    add2(dw2, 2000, 500, 512, 2048, dw2h);
    add2(dw3, 500, 500, 512, 512, dw3h);
    add2(xw,  500, 2000, 2048, 512, xwh);
    add2(g2,  500, 500, 512, 512, g2h);
    add2(g3,  500, 2000, 2048, 512, g3h);
    cp.tile0[9] = nt;
    k_conv_bt_all<<<nt, b256, 0, stream>>>(cp);
  }
  k_build_wc<<<(128*3136+255)/256, b256, 0, stream>>>(mlw, g5, wch);

  const int MT = Mp/128;   // 157
  #define HGEMM(ACT,BIAS, A_,BT_,BIASP_,CH_, NV_,NP_,KP_,LDA_) \
    k_hgemm<ACT,BIAS><<<dim3((NP_)/128, MT), b256, 0, stream>>>( \
      (A_),(BT_),(BIASP_),(CH_), N, (NV_), (NP_), (KP_), (LDA_))

  // ---- encoder + first GCN layer fused on the x pass ----
  k_hgemm_dual<<<dim3(8, MT), b256, 0, stream>>>(xh, ewg1h, eb1, dualh, N);                // tra1h|pre1h
  HGEMM(1,true,  dualh, ew2h, eb2, tra2h, 500, 512, 512, 1024);                            // tra2h
  HGEMM(1,true,  tra2h, ew3h, eb3, tra3h, 2000, 2048, 512, 512);                           // tra3h
  k_skinny10_h<<<512, b256, 0, stream>>>(tra3h, 2048, zw, 2000, zb, zlat, N, 0);           // zlat

  // ---- GCN branch ----
  k_spmm2<2><<<N, b256, 0, stream>>>(dualh+512, 1024, rp, ci, nsrc, ndst, z1h, H1, 512);   // z1h (leaky)
  k_gate_mix_hh<<<N, b256, 0, stream>>>(dualh, 1024, z1h, 512, m1w, m1b, Qh, H1, 512);     // mix1h
  k_spmm2<0><<<N, b256, 0, stream>>>(Qh, 512, rp, ci, nsrc, ndst, Ph, H1, 512);            // agg2h
  HGEMM(2,false, Ph, g2h, nullptr, z2h, 500, 512, 512, 512);                               // z2h (leaky)
  k_gate_mix_hh<<<N, b256, 0, stream>>>(tra2h, 512, z2h, 512, m2w, m2b, Qh, H2, 512);      // mix2h
  k_spmm2<0><<<N, b256, 0, stream>>>(Qh, 512, rp, ci, nsrc, ndst, Ph, H2, 512);            // agg3h
  HGEMM(2,false, Ph, g3h, nullptr, xh, 2000, 2048, 512, 512);                              // z3h (xh slot)
  k_fused3<<<512, b256, 0, stream>>>(tra3h, xh, m3w, m3b, g4, pre4, N);                    // gate3 + mix@g4
  k_spmm10<2><<<(N*10+255)/256, b256, 0, stream>>>(pre4, rp, ci, nsrc, ndst, z4, N);       // z4
  k_tail64<<<(N*64+255)/256, b256, 0, stream>>>(z4, zlat, z4zh, N);
  k_hgemm_up5<<<dim3(2, MT), b256, 0, stream>>>(z1h, z2h, xh, z4zh, wch, Ybuf, N, Mp);
  k_up5_fin<<<(N+255)/256, b256, 0, stream>>>(Ybuf, mlb, pre5, N, Mp);
  k_spmm10<0><<<(N*10+255)/256, b256, 0, stream>>>(pre5, rp, ci, nsrc, ndst, hbuf, N);
  k_softmax10<<<(N+255)/256, b256, 0, stream>>>(hbuf, out_pred, N);
  // ---- clustering head ----
  k_q<<<(N+255)/256, b256, 0, stream>>>(zlat, cluster, out_q, colsum, N);
  k_p<<<(N+255)/256, b256, 0, stream>>>(out_q, colsum, out_p, N);

  // ---- decoder (xh/z3h dead after up5 GEMM) ----
  k_broad_reg<<<512, 512, 0, stream>>>(zlat, dw1, db1, xh, N, Mp, H3, 2048);               // dh1h
  HGEMM(1,true,  xh, dw2h, db2, Qh, 500, 512, 2048, 2048);                                 // dh2h
  HGEMM(1,true,  Qh, dw3h, db3, Ph, 500, 512, 512, 512);                                   // dh3h
  k_hgemm_f32t<<<dim3(16, MT), b256, 0, stream>>>(Ph, xwh, xb, out_xbar, N, 2000, 512, 512); // x_bar
  #undef HGEMM
}